// Round 6
// baseline (208.391 us; speedup 1.0000x reference)
//
#include <hip/hip_runtime.h>
#include <hip/hip_bf16.h>
#include <math.h>

#define IN_DIM 384
#define HID 16
#define NCLS 2
#define BN_EPS 1e-5f
#define MAXG 64

#define LOF(u) __uint_as_float((u) << 16)
#define HIF(u) __uint_as_float((u) & 0xffff0000u)

__device__ __forceinline__ unsigned packbf(float a, float b) {  // RNE, monotone
    __hip_bfloat162 h2 = __float22bfloat162_rn(make_float2(a, b));
    union { __hip_bfloat162 h; unsigned u; } c;
    c.h = h2;
    return c.u;  // low 16 bits = a
}

// ---------------- CSR build ----------------
__global__ void k_hist(const int* __restrict__ ei, int E, int* __restrict__ deg) {
    int stride = gridDim.x * blockDim.x;
    for (int e = blockIdx.x * blockDim.x + threadIdx.x; e < E; e += stride)
        atomicAdd(&deg[ei[e]], 1);
}

__global__ void k_alloc(const int* __restrict__ deg, int N, int2* __restrict__ degoffs,
                        int* __restrict__ wcur, int* __restrict__ cursor) {
    int i = blockIdx.x * blockDim.x + threadIdx.x;
    int lane = threadIdx.x & 63;
    int d = (i < N) ? deg[i] : 0;
    int run = d;
#pragma unroll
    for (int s = 1; s < 64; s <<= 1) {
        int v = __shfl_up(run, s, 64);
        if (lane >= s) run += v;
    }
    int total = __shfl(run, 63, 64);
    int base = 0;
    if (lane == 63) base = atomicAdd(cursor, total);
    base = __shfl(base, 63, 64);
    if (i < N) {
        int o = base + run - d;
        degoffs[i] = make_int2(o, d);
        wcur[i] = o;
    }
}

__global__ void k_scatter(const int* __restrict__ ei, const int* __restrict__ ej, int E,
                          int* __restrict__ wcur, int* __restrict__ colidx) {
    int stride = gridDim.x * blockDim.x;
    for (int e = blockIdx.x * blockDim.x + threadIdx.x; e < E; e += stride) {
        int i = ei[e];
        int pos = atomicAdd(&wcur[i], 1);
        colidx[pos] = ej[e];
    }
}

// ---------------- pre-projection (wave per 4 nodes, LOOPED with x prefetch):
// y[i][0..15] = x@W_mean.T, y[i][16..31] = x@W_root.T; emits bf16 copy xb.
__global__ __launch_bounds__(256) void k_proj(const float* __restrict__ x,
                                              const float* __restrict__ wl,
                                              const float* __restrict__ wr, int N,
                                              float* __restrict__ y,
                                              unsigned* __restrict__ xb) {
    int lane = threadIdx.x & 63;
    int wid = threadIdx.x >> 6;
    int kq = ((lane >> 4) << 2) + (lane & 3);
    int nq = (lane & 15) >> 2;
    int ngroups = (N + 3) >> 2;
    int gw = blockIdx.x * 4 + wid;
    int gstride = gridDim.x * 4;
    if (gw >= ngroups) return;
    float2 xn[4][3];
    {
        int ibase = gw << 2;
#pragma unroll
        for (int n = 0; n < 4; n++) {
            int i = min(ibase + n, N - 1);
            const float* xr = x + (size_t)i * IN_DIM + 2 * lane;
            xn[n][0] = *(const float2*)xr;
            xn[n][1] = *(const float2*)(xr + 128);
            xn[n][2] = *(const float2*)(xr + 256);
        }
    }
    for (int g = gw; g < ngroups; g += gstride) {
        int ibase = g << 2;
        float2 xv[4][3];
#pragma unroll
        for (int n = 0; n < 4; n++)
#pragma unroll
            for (int c = 0; c < 3; c++) xv[n][c] = xn[n][c];
        int gnext = g + gstride;
        if (gnext < ngroups) {  // prefetch next group's x under this group's compute
            int ib2 = gnext << 2;
#pragma unroll
            for (int n = 0; n < 4; n++) {
                int i = min(ib2 + n, N - 1);
                const float* xr = x + (size_t)i * IN_DIM + 2 * lane;
                xn[n][0] = *(const float2*)xr;
                xn[n][1] = *(const float2*)(xr + 128);
                xn[n][2] = *(const float2*)(xr + 256);
            }
        }
#pragma unroll
        for (int n = 0; n < 4; n++) {
            int i = ibase + n;
            if (i < N) {
                unsigned* xo = xb + (size_t)i * 192 + lane;
#pragma unroll
                for (int c = 0; c < 3; c++)
                    xo[c * 64] = packbf(xv[n][c].x, xv[n][c].y);
            }
        }
        float out0 = 0.f, out1 = 0.f;
#pragma unroll
        for (int kg = 0; kg < 8; kg++) {
            float r[16];
#pragma unroll
            for (int kk = 0; kk < 4; kk++) {
                int k = ((kg & 3) << 2) + kk;
                const float* wrow = (kg < 4) ? (wl + (size_t)k * (2 * IN_DIM) + 2 * lane)
                                             : (wr + (size_t)k * IN_DIM + 2 * lane);
                float2 w0 = *(const float2*)wrow;
                float2 w1 = *(const float2*)(wrow + 128);
                float2 w2 = *(const float2*)(wrow + 256);
#pragma unroll
                for (int n = 0; n < 4; n++) {
                    float t = xv[n][0].x * w0.x;
                    t = fmaf(xv[n][0].y, w0.y, t);
                    t = fmaf(xv[n][1].x, w1.x, t);
                    t = fmaf(xv[n][1].y, w1.y, t);
                    t = fmaf(xv[n][2].x, w2.x, t);
                    t = fmaf(xv[n][2].y, w2.y, t);
                    r[(n << 2) + kk] = t;
                }
            }
#pragma unroll
            for (int st = 0; st < 4; st++) {
                int step = 1 << st;
                bool hi = (lane & step) != 0;
#pragma unroll
                for (int m = 0; m < (8 >> st); m++) {
                    float a = r[2 * m], b = r[2 * m + 1];
                    float send = hi ? a : b;
                    float keep = hi ? b : a;
                    r[m] = keep + __shfl_xor(send, step, 64);
                }
            }
            float v = r[0];
            v += __shfl_xor(v, 16, 64);
            v += __shfl_xor(v, 32, 64);
            if ((lane >> 4) == (kg & 3)) {
                if (kg < 4) out0 = v;
                else out1 = v;
            }
        }
        int iw = ibase + nq;
        if (iw < N) {
            y[(size_t)iw * 32 + kq] = out0;
            y[(size_t)iw * 32 + 16 + kq] = out1;
        }
    }
}

// ---------------- wave-per-4-nodes: 4-node-CONCURRENT bf16 gather-max
// (48 loads in flight), projection through global W_max, reduce-scatter,
// fused BN-stats. LDS ~= 128 B.
__global__ __launch_bounds__(256) void k_node(const unsigned* __restrict__ xb,
                                              const float* __restrict__ y,
                                              const float* __restrict__ wl,
                                              const float* __restrict__ lb,
                                              const int2* __restrict__ degoffs,
                                              const int* __restrict__ colidx, int N,
                                              float* __restrict__ h,
                                              float* __restrict__ stats) {
    __shared__ float shS[32];
    if (threadIdx.x < 32) shS[threadIdx.x] = 0.f;
    __syncthreads();
    int lane = threadIdx.x & 63;
    int wid = threadIdx.x >> 6;
    int kq = ((lane >> 4) << 2) + (lane & 3);  // channel this lane finalizes
    int nq = (lane & 15) >> 2;                 // node slot this lane finalizes
    int slot = lane >> 4;                      // edge slot for y-gather
    int ch = lane & 15;                        // y channel for y-gather
    float sAcc = 0.f, s2Acc = 0.f;
    int ngroups = (N + 3) >> 2;
    int g = blockIdx.x * 4 + wid;
    if (g < ngroups) {
        int ibase = g << 2;
        int2 dof[4];
        int jpre[4];
        int dgv[4];
#pragma unroll
        for (int n = 0; n < 4; n++)
            dof[n] = (ibase + n < N) ? degoffs[ibase + n] : make_int2(0, 0);
#pragma unroll
        for (int n = 0; n < 4; n++) {
            dgv[n] = dof[n].y;
            jpre[n] = (dof[n].y > 0) ? colidx[dof[n].x + min(lane, dof[n].y - 1)] : 0;
        }
        float2 mx[4][3];
        float sd[4];
#pragma unroll
        for (int n = 0; n < 4; n++) {
            mx[n][0] = make_float2(-INFINITY, -INFINITY);
            mx[n][1] = mx[n][0];
            mx[n][2] = mx[n][0];
            sd[n] = 0.f;
        }
        int mxd = max(max(dgv[0], dgv[1]), max(dgv[2], dgv[3]));
        if (mxd <= 64) {
            // fast path: all 4 nodes' edges fit one jpre vector; process one
            // 4-edge chunk of EVERY active node per round (up to 52 loads in flight)
            for (int eb = 0; eb < mxd; eb += 4) {
                unsigned v[4][4][3];
                float yv[4];
                bool ym[4];
#pragma unroll
                for (int n = 0; n < 4; n++) {
                    bool act = eb < dgv[n];
                    int j0 = __shfl(jpre[n], eb, 64);
                    int j1 = __shfl(jpre[n], eb + 1, 64);
                    int j2 = __shfl(jpre[n], eb + 2, 64);
                    int j3 = __shfl(jpre[n], eb + 3, 64);
                    if (act) {
                        const unsigned* q0 = xb + (size_t)j0 * 192 + lane;
                        const unsigned* q1 = xb + (size_t)j1 * 192 + lane;
                        const unsigned* q2 = xb + (size_t)j2 * 192 + lane;
                        const unsigned* q3 = xb + (size_t)j3 * 192 + lane;
#pragma unroll
                        for (int w = 0; w < 3; w++) {
                            v[n][0][w] = q0[w * 64];
                            v[n][1][w] = q1[w * 64];
                            v[n][2][w] = q2[w * 64];
                            v[n][3][w] = q3[w * 64];
                        }
                        int js = (slot == 0) ? j0 : (slot == 1) ? j1 : (slot == 2) ? j2 : j3;
                        yv[n] = y[(size_t)js * 32 + ch];
                        ym[n] = (eb + slot < dgv[n]);
                    } else {
#pragma unroll
                        for (int e = 0; e < 4; e++)
#pragma unroll
                            for (int w = 0; w < 3; w++) v[n][e][w] = 0xFF80FF80u;  // -inf|-inf
                        yv[n] = 0.f;
                        ym[n] = false;
                    }
                }
#pragma unroll
                for (int n = 0; n < 4; n++) {
                    sd[n] += ym[n] ? yv[n] : 0.f;
#pragma unroll
                    for (int w = 0; w < 3; w++) {
                        float lo = fmaxf(fmaxf(LOF(v[n][0][w]), LOF(v[n][1][w])),
                                         fmaxf(LOF(v[n][2][w]), LOF(v[n][3][w])));
                        float hi = fmaxf(fmaxf(HIF(v[n][0][w]), HIF(v[n][1][w])),
                                         fmaxf(HIF(v[n][2][w]), HIF(v[n][3][w])));
                        if (w == 0) { mx[n][0].x = fmaxf(mx[n][0].x, lo); mx[n][0].y = fmaxf(mx[n][0].y, hi); }
                        if (w == 1) { mx[n][1].x = fmaxf(mx[n][1].x, lo); mx[n][1].y = fmaxf(mx[n][1].y, hi); }
                        if (w == 2) { mx[n][2].x = fmaxf(mx[n][2].x, lo); mx[n][2].y = fmaxf(mx[n][2].y, hi); }
                    }
                }
            }
        } else {
            // general path: sequential per node (rare: deg > 64)
#pragma unroll
            for (int n = 0; n < 4; n++) {
                int beg = dof[n].x, dg = dgv[n];
                for (int e0 = 0; e0 < dg; e0 += 64) {
                    int nv = min(64, dg - e0);
                    int jv = (e0 == 0) ? jpre[n] : colidx[beg + min(e0 + lane, dg - 1)];
                    for (int eb = 0; eb < nv; eb += 4) {
                        int j0 = __shfl(jv, eb, 64);
                        int j1 = __shfl(jv, eb + 1, 64);
                        int j2 = __shfl(jv, eb + 2, 64);
                        int j3 = __shfl(jv, eb + 3, 64);
                        const unsigned* q0 = xb + (size_t)j0 * 192 + lane;
                        const unsigned* q1 = xb + (size_t)j1 * 192 + lane;
                        const unsigned* q2 = xb + (size_t)j2 * 192 + lane;
                        const unsigned* q3 = xb + (size_t)j3 * 192 + lane;
                        unsigned a0 = q0[0], a1 = q0[64], a2 = q0[128];
                        unsigned b0 = q1[0], b1 = q1[64], b2 = q1[128];
                        unsigned c0 = q2[0], c1 = q2[64], c2 = q2[128];
                        unsigned d0 = q3[0], d1 = q3[64], d2 = q3[128];
                        int js = (slot == 0) ? j0 : (slot == 1) ? j1 : (slot == 2) ? j2 : j3;
                        float yv = y[(size_t)js * 32 + ch];
                        sd[n] += (eb + slot < nv) ? yv : 0.f;
                        mx[n][0].x = fmaxf(fmaxf(mx[n][0].x, fmaxf(LOF(a0), LOF(b0))), fmaxf(LOF(c0), LOF(d0)));
                        mx[n][0].y = fmaxf(fmaxf(mx[n][0].y, fmaxf(HIF(a0), HIF(b0))), fmaxf(HIF(c0), HIF(d0)));
                        mx[n][1].x = fmaxf(fmaxf(mx[n][1].x, fmaxf(LOF(a1), LOF(b1))), fmaxf(LOF(c1), LOF(d1)));
                        mx[n][1].y = fmaxf(fmaxf(mx[n][1].y, fmaxf(HIF(a1), HIF(b1))), fmaxf(HIF(c1), HIF(d1)));
                        mx[n][2].x = fmaxf(fmaxf(mx[n][2].x, fmaxf(LOF(a2), LOF(b2))), fmaxf(LOF(c2), LOF(d2)));
                        mx[n][2].y = fmaxf(fmaxf(mx[n][2].y, fmaxf(HIF(a2), HIF(b2))), fmaxf(HIF(c2), HIF(d2)));
                    }
                }
            }
        }
#pragma unroll
        for (int n = 0; n < 4; n++) {
            if (dgv[n] == 0) {  // wave-uniform; isolated/invalid -> max_agg = 0
                mx[n][0] = make_float2(0.f, 0.f);
                mx[n][1] = mx[n][0];
                mx[n][2] = mx[n][0];
            }
            sd[n] += __shfl_xor(sd[n], 16, 64);
            sd[n] += __shfl_xor(sd[n], 32, 64);
        }
        // projection: W_max from global (L1-hot 24 KB); one sweep serves 4 nodes
        const float* wp = wl + IN_DIM + 2 * lane;
        float outv = 0.f;
#pragma unroll
        for (int kg = 0; kg < 4; kg++) {
            float r[16];
#pragma unroll
            for (int kk = 0; kk < 4; kk++) {
                int k = (kg << 2) + kk;
                const float* wrow = wp + (size_t)k * (2 * IN_DIM);
                float2 w0 = *(const float2*)wrow;
                float2 w1 = *(const float2*)(wrow + 128);
                float2 w2 = *(const float2*)(wrow + 256);
#pragma unroll
                for (int n = 0; n < 4; n++) {
                    float t = mx[n][0].x * w0.x;
                    t = fmaf(mx[n][0].y, w0.y, t);
                    t = fmaf(mx[n][1].x, w1.x, t);
                    t = fmaf(mx[n][1].y, w1.y, t);
                    t = fmaf(mx[n][2].x, w2.x, t);
                    t = fmaf(mx[n][2].y, w2.y, t);
                    r[(n << 2) + kk] = t;
                }
            }
#pragma unroll
            for (int st = 0; st < 4; st++) {
                int step = 1 << st;
                bool hi = (lane & step) != 0;
#pragma unroll
                for (int m = 0; m < (8 >> st); m++) {
                    float a = r[2 * m], b = r[2 * m + 1];
                    float send = hi ? a : b;
                    float keep = hi ? b : a;
                    r[m] = keep + __shfl_xor(send, step, 64);
                }
            }
            float v = r[0];
            v += __shfl_xor(v, 16, 64);
            v += __shfl_xor(v, 32, 64);
            if ((lane >> 4) == kg) outv = v;
        }
        // epilogue: lane owns (node nq, channel kq); contiguous h-write
        int iw = ibase + nq;
        float t0 = __shfl(sd[0], kq, 64), t1 = __shfl(sd[1], kq, 64);
        float t2 = __shfl(sd[2], kq, 64), t3 = __shfl(sd[3], kq, 64);
        float sv = (nq == 0) ? t0 : (nq == 1) ? t1 : (nq == 2) ? t2 : t3;
        int dgs = (nq == 0) ? dgv[0] : (nq == 1) ? dgv[1] : (nq == 2) ? dgv[2] : dgv[3];
        if (iw < N) {
            float mean = sv / (float)max(dgs, 1);
            float hv = mean + outv + y[(size_t)iw * 32 + 16 + kq] + lb[kq];
            h[(size_t)iw * HID + kq] = hv;
            sAcc += hv;
            s2Acc = fmaf(hv, hv, s2Acc);
        }
    }
    __syncthreads();
    atomicAdd(&shS[kq], sAcc);
    atomicAdd(&shS[16 + kq], s2Acc);
    __syncthreads();
    if (threadIdx.x < 32) atomicAdd(&stats[threadIdx.x], shS[threadIdx.x]);
}

// ---------------- BN + ReLU + global mean pool + (last block) FC
__global__ __launch_bounds__(256) void k_pool(const float* __restrict__ h,
                                              const int* __restrict__ batch,
                                              const float* __restrict__ stats,
                                              const float* __restrict__ gamma,
                                              const float* __restrict__ beta, int N,
                                              float* __restrict__ pooled,
                                              int* __restrict__ gcnt,
                                              int* __restrict__ ticket,
                                              const float* __restrict__ fcw,
                                              const float* __restrict__ fcb, int G,
                                              float* __restrict__ out) {
    __shared__ float smP[MAXG * HID];
    __shared__ int smC[MAXG];
    __shared__ int isLast;
    for (int idx = threadIdx.x; idx < MAXG * HID; idx += blockDim.x) smP[idx] = 0.f;
    if (threadIdx.x < MAXG) smC[threadIdx.x] = 0;
    __syncthreads();
    int c = threadIdx.x & 15;
    float invN = 1.f / (float)N;
    float mu = stats[c] * invN;
    float var = stats[16 + c] * invN - mu * mu;
    float sc = gamma[c] * rsqrtf(var + BN_EPS);
    float sh = beta[c] - mu * sc;
    int base = blockIdx.x * 1024;
    int endn = min(base + 1024, N);
    for (int idx = base * HID + threadIdx.x; idx < endn * HID; idx += blockDim.x) {
        int n = idx >> 4;
        float v = fmaxf(fmaf(h[idx], sc, sh), 0.f);
        int g = batch[n] & (MAXG - 1);
        atomicAdd(&smP[g * HID + c], v);
        if (c == 0) atomicAdd(&smC[g], 1);
    }
    __syncthreads();
    for (int idx = threadIdx.x; idx < MAXG * HID; idx += blockDim.x)
        if (smP[idx] != 0.f) atomicAdd(&pooled[idx], smP[idx]);
    if (threadIdx.x < MAXG && smC[threadIdx.x]) atomicAdd(&gcnt[threadIdx.x], smC[threadIdx.x]);
    __threadfence();
    __syncthreads();
    if (threadIdx.x == 0) {
        int t = atomicAdd(ticket, 1);
        isLast = (t == (int)gridDim.x - 1);
    }
    __syncthreads();
    if (isLast && threadIdx.x < G) {
        int g = threadIdx.x;
        __threadfence();
        int cnt = atomicAdd(&gcnt[g], 0);  // coherent read (cross-XCD safe)
        float inv = 1.f / (float)max(cnt, 1);
        float o0 = fcb[0], o1 = fcb[1];
#pragma unroll
        for (int chh = 0; chh < HID; chh++) {
            float pv = atomicAdd(&pooled[g * HID + chh], 0.f) * inv;
            o0 = fmaf(pv, fcw[chh], o0);
            o1 = fmaf(pv, fcw[HID + chh], o1);
        }
        out[g * NCLS + 0] = o0;
        out[g * NCLS + 1] = o1;
    }
}

extern "C" void kernel_launch(void* const* d_in, const int* in_sizes, int n_in,
                              void* d_out, int out_size, void* d_ws, size_t ws_size,
                              hipStream_t stream) {
    const float* x = (const float*)d_in[0];
    const int* ei = (const int*)d_in[1];
    const int* batch = (const int*)d_in[2];
    const float* wl = (const float*)d_in[4];
    const float* lb = (const float*)d_in[5];
    const float* wr = (const float*)d_in[6];
    const float* gamma = (const float*)d_in[7];
    const float* beta = (const float*)d_in[8];
    const float* fcw = (const float*)d_in[9];
    const float* fcb = (const float*)d_in[10];

    const int N = in_sizes[0] / IN_DIM;
    const int E = in_sizes[1] / 2;
    const int G = out_size / NCLS;
    const int* ej = ei + E;

    size_t off = 0;
    auto take = [&](size_t b) { size_t r = off; off += (b + 255) & ~(size_t)255; return r; };
    size_t deg_off  = take((size_t)N * 4);
    size_t cur_off  = take(4);
    size_t stat_off = take(32 * 4);
    size_t pool_off = take((size_t)MAXG * HID * 4);
    size_t gcnt_off = take((size_t)MAXG * 4);
    size_t tick_off = take(4);
    size_t zero_bytes = off;
    size_t dof_off  = take((size_t)N * 8);
    size_t wcur_off = take((size_t)N * 4);
    size_t col_off  = take((size_t)E * 4);
    size_t y_off    = take((size_t)N * 32 * 4);
    size_t h_off    = take((size_t)N * HID * 4);
    size_t xb_off   = take((size_t)N * 192 * 4);
    (void)ws_size;

    char* ws = (char*)d_ws;
    int* deg = (int*)(ws + deg_off);
    int* cursor = (int*)(ws + cur_off);
    float* stats = (float*)(ws + stat_off);
    float* pooled = (float*)(ws + pool_off);
    int* gcnt = (int*)(ws + gcnt_off);
    int* ticket = (int*)(ws + tick_off);
    int2* degoffs = (int2*)(ws + dof_off);
    int* wcur = (int*)(ws + wcur_off);
    int* colidx = (int*)(ws + col_off);
    float* y = (float*)(ws + y_off);
    float* h = (float*)(ws + h_off);
    unsigned* xb = (unsigned*)(ws + xb_off);

    hipMemsetAsync(d_ws, 0, zero_bytes, stream);

    int eblocks = (E + 255) / 256;
    int ngroups = (N + 3) >> 2;
    int gblocks = (ngroups + 3) / 4;
    int pblocks = (ngroups + 15) / 16;  // ~4 groups per wave in k_proj
    if (pblocks < 1) pblocks = 1;
    k_hist<<<eblocks, 256, 0, stream>>>(ei, E, deg);
    k_alloc<<<(N + 255) / 256, 256, 0, stream>>>(deg, N, degoffs, wcur, cursor);
    k_scatter<<<eblocks, 256, 0, stream>>>(ei, ej, E, wcur, colidx);
    k_proj<<<pblocks, 256, 0, stream>>>(x, wl, wr, N, y, xb);
    k_node<<<gblocks, 256, 0, stream>>>(xb, y, wl, lb, degoffs, colidx, N, h, stats);
    k_pool<<<(N + 1023) / 1024, 256, 0, stream>>>(h, batch, stats, gamma, beta, N, pooled,
                                                  gcnt, ticket, fcw, fcb, G, (float*)d_out);
}

// Round 7
// 168.603 us; speedup vs baseline: 1.2360x; 1.2360x over previous
//
#include <hip/hip_runtime.h>
#include <hip/hip_bf16.h>
#include <math.h>

#define IN_DIM 384
#define HID 16
#define NCLS 2
#define BN_EPS 1e-5f
#define MAXG 64

#define LOF(u) __uint_as_float((u) << 16)
#define HIF(u) __uint_as_float((u) & 0xffff0000u)

typedef __attribute__((ext_vector_type(8))) short bf16x8;
typedef __attribute__((ext_vector_type(4))) float f32x4;

__device__ __forceinline__ unsigned packbf(float a, float b) {  // RNE, monotone; low16 = a
    __hip_bfloat162 h2 = __float22bfloat162_rn(make_float2(a, b));
    union { __hip_bfloat162 h; unsigned u; } c;
    c.h = h2;
    return c.u;
}

// ---------------- CSR hist + (block 0) bf16 weight conversion ----------------
__global__ void k_hist(const int* __restrict__ ei, int E, int* __restrict__ deg,
                       const float* __restrict__ wl, const float* __restrict__ wr,
                       unsigned* __restrict__ wbm, unsigned* __restrict__ wbr) {
    if (blockIdx.x == 0) {
        for (int w = threadIdx.x; w < 16 * 192; w += blockDim.x) {
            int r = w / 192, c = w - r * 192;
            wbm[w] = packbf(wl[r * 768 + 2 * c], wl[r * 768 + 2 * c + 1]);  // mean part
            wbr[w] = packbf(wr[r * 384 + 2 * c], wr[r * 384 + 2 * c + 1]);  // root part
        }
    }
    int stride = gridDim.x * blockDim.x;
    for (int e = blockIdx.x * blockDim.x + threadIdx.x; e < E; e += stride)
        atomicAdd(&deg[ei[e]], 1);
}

__global__ void k_alloc(const int* __restrict__ deg, int N, int2* __restrict__ degoffs,
                        int* __restrict__ wcur, int* __restrict__ cursor) {
    int i = blockIdx.x * blockDim.x + threadIdx.x;
    int lane = threadIdx.x & 63;
    int d = (i < N) ? deg[i] : 0;
    int run = d;
#pragma unroll
    for (int s = 1; s < 64; s <<= 1) {
        int v = __shfl_up(run, s, 64);
        if (lane >= s) run += v;
    }
    int total = __shfl(run, 63, 64);
    int base = 0;
    if (lane == 63) base = atomicAdd(cursor, total);
    base = __shfl(base, 63, 64);
    if (i < N) {
        int o = base + run - d;
        degoffs[i] = make_int2(o, d);
        wcur[i] = o;
    }
}

__global__ void k_scatter(const int* __restrict__ ei, const int* __restrict__ ej, int E,
                          int* __restrict__ wcur, int* __restrict__ colidx) {
    int stride = gridDim.x * blockDim.x;
    for (int e = blockIdx.x * blockDim.x + threadIdx.x; e < E; e += stride) {
        int i = ei[e];
        int pos = atomicAdd(&wcur[i], 1);
        colidx[pos] = ej[e];
    }
}

// ---------------- MFMA pre-projection: wave per 16 nodes.
// y[i][0..15] = x@W_mean.T, y[i][16..31] = x@W_root.T; emits bf16 copy xb.
// A = W (16 rows x K), B = x^T (K x 16 nodes): both frags use the mirrored
// row/col=lane&15, k=(lane>>4)*8+i rule (k-permutation cancels between A,B);
// D col=lane&15=node, row=(lane>>4)*4+reg=channel (m89-verified) -> float4 y store.
__global__ __launch_bounds__(256) void k_proj(const float* __restrict__ x,
                                              const unsigned* __restrict__ wbm,
                                              const unsigned* __restrict__ wbr,
                                              int N, float* __restrict__ y,
                                              unsigned* __restrict__ xb) {
    int lane = threadIdx.x & 63;
    int tile = blockIdx.x * 4 + (threadIdx.x >> 6);
    int ntiles = (N + 15) >> 4;
    if (tile >= ntiles) return;
    int row = lane & 15;  // node-within-tile == weight row lane
    int g = lane >> 4;    // k-group of 8 dims
    int node = tile * 16 + row;
    int nodec = min(node, N - 1);
    bool ok = (node < N);
    const float* xr = x + (size_t)nodec * IN_DIM + g * 8;
    const uint4* wm = (const uint4*)(wbm + (size_t)row * 192 + g * 4);
    const uint4* wq = (const uint4*)(wbr + (size_t)row * 192 + g * 4);
    uint4* xo = (uint4*)(xb + (size_t)nodec * 192 + g * 4);
    f32x4 acc0 = {0.f, 0.f, 0.f, 0.f};
    f32x4 acc1 = {0.f, 0.f, 0.f, 0.f};
#pragma unroll
    for (int c = 0; c < 12; c++) {
        float4 xa = *(const float4*)(xr + c * 32);
        float4 xc = *(const float4*)(xr + c * 32 + 4);
        union { uint4 u; bf16x8 v; } xf, wa, wb;
        xf.u.x = packbf(xa.x, xa.y);
        xf.u.y = packbf(xa.z, xa.w);
        xf.u.z = packbf(xc.x, xc.y);
        xf.u.w = packbf(xc.z, xc.w);
        if (ok) xo[c * 4] = xf.u;  // word offset c*16: dims [c*32+g*8, +8)
        wa.u = wm[c * 4];
        wb.u = wq[c * 4];
        acc0 = __builtin_amdgcn_mfma_f32_16x16x32_bf16(wa.v, xf.v, acc0, 0, 0, 0);
        acc1 = __builtin_amdgcn_mfma_f32_16x16x32_bf16(wb.v, xf.v, acc1, 0, 0, 0);
    }
    if (ok) {
        float* yo = y + (size_t)node * 32 + g * 4;
        *(float4*)yo = make_float4(acc0[0], acc0[1], acc0[2], acc0[3]);
        *(float4*)(yo + 16) = make_float4(acc1[0], acc1[1], acc1[2], acc1[3]);
    }
}

// ---------------- wave-per-4-nodes: bf16 gather-max (padded 4-edge chunks,
// duplicate edges idempotent for max, masked for mean-sum), projection through
// global W_max (L1/L2-hot), reduce-scatter, fused BN-stats. LDS ~= 128 B.
__global__ __launch_bounds__(256) void k_node(const unsigned* __restrict__ xb,
                                              const float* __restrict__ y,
                                              const float* __restrict__ wl,
                                              const float* __restrict__ lb,
                                              const int2* __restrict__ degoffs,
                                              const int* __restrict__ colidx, int N,
                                              float* __restrict__ h,
                                              float* __restrict__ stats) {
    __shared__ float shS[32];
    if (threadIdx.x < 32) shS[threadIdx.x] = 0.f;
    __syncthreads();
    int lane = threadIdx.x & 63;
    int wid = threadIdx.x >> 6;
    int kq = ((lane >> 4) << 2) + (lane & 3);  // channel this lane finalizes
    int nq = (lane & 15) >> 2;                 // node slot this lane finalizes
    int slot = lane >> 4;                      // edge slot for y-gather
    int ch = lane & 15;                        // y channel for y-gather
    float sAcc = 0.f, s2Acc = 0.f;
    int ngroups = (N + 3) >> 2;
    int g = blockIdx.x * 4 + wid;
    if (g < ngroups) {
        int ibase = g << 2;
        int2 dof[4];
        int jpre[4];
#pragma unroll
        for (int n = 0; n < 4; n++)
            dof[n] = (ibase + n < N) ? degoffs[ibase + n] : make_int2(0, 0);
#pragma unroll
        for (int n = 0; n < 4; n++)
            jpre[n] = (dof[n].y > 0) ? colidx[dof[n].x + min(lane, dof[n].y - 1)] : 0;
        float2 mx[4][3];
        float sd[4];
        int dgv[4];
#pragma unroll
        for (int n = 0; n < 4; n++) {
            int beg = dof[n].x, dg = dof[n].y;
            dgv[n] = dg;
            float2 m0 = make_float2(-INFINITY, -INFINITY), m1 = m0, m2 = m0;
            float s = 0.f;
            for (int e0 = 0; e0 < dg; e0 += 64) {
                int nv = min(64, dg - e0);
                int jv = (e0 == 0) ? jpre[n] : colidx[beg + min(e0 + lane, dg - 1)];
                for (int eb = 0; eb < nv; eb += 4) {
                    int j0 = __shfl(jv, eb, 64);
                    int j1 = __shfl(jv, eb + 1, 64);
                    int j2 = __shfl(jv, eb + 2, 64);
                    int j3 = __shfl(jv, eb + 3, 64);
                    const unsigned* q0 = xb + (size_t)j0 * 192 + lane;
                    const unsigned* q1 = xb + (size_t)j1 * 192 + lane;
                    const unsigned* q2 = xb + (size_t)j2 * 192 + lane;
                    const unsigned* q3 = xb + (size_t)j3 * 192 + lane;
                    unsigned a0 = q0[0], a1 = q0[64], a2 = q0[128];
                    unsigned b0 = q1[0], b1 = q1[64], b2 = q1[128];
                    unsigned c0 = q2[0], c1 = q2[64], c2 = q2[128];
                    unsigned d0 = q3[0], d1 = q3[64], d2 = q3[128];
                    int js = (slot == 0) ? j0 : (slot == 1) ? j1 : (slot == 2) ? j2 : j3;
                    float yv = y[(size_t)js * 32 + ch];
                    s += (eb + slot < nv) ? yv : 0.f;
                    m0.x = fmaxf(fmaxf(m0.x, fmaxf(LOF(a0), LOF(b0))), fmaxf(LOF(c0), LOF(d0)));
                    m0.y = fmaxf(fmaxf(m0.y, fmaxf(HIF(a0), HIF(b0))), fmaxf(HIF(c0), HIF(d0)));
                    m1.x = fmaxf(fmaxf(m1.x, fmaxf(LOF(a1), LOF(b1))), fmaxf(LOF(c1), LOF(d1)));
                    m1.y = fmaxf(fmaxf(m1.y, fmaxf(HIF(a1), HIF(b1))), fmaxf(HIF(c1), HIF(d1)));
                    m2.x = fmaxf(fmaxf(m2.x, fmaxf(LOF(a2), LOF(b2))), fmaxf(LOF(c2), LOF(d2)));
                    m2.y = fmaxf(fmaxf(m2.y, fmaxf(HIF(a2), HIF(b2))), fmaxf(HIF(c2), HIF(d2)));
                }
            }
            if (dg == 0) {  // wave-uniform; isolated/invalid -> max_agg = 0
                m0 = make_float2(0.f, 0.f); m1 = m0; m2 = m0;
            }
            mx[n][0] = m0; mx[n][1] = m1; mx[n][2] = m2;
            sd[n] = s;
        }
#pragma unroll
        for (int n = 0; n < 4; n++) {
            sd[n] += __shfl_xor(sd[n], 16, 64);
            sd[n] += __shfl_xor(sd[n], 32, 64);
        }
        // projection: W_max from global (L1-hot 24 KB); one sweep serves 4 nodes
        const float* wp = wl + IN_DIM + 2 * lane;
        float outv = 0.f;
#pragma unroll
        for (int kg = 0; kg < 4; kg++) {
            float r[16];
#pragma unroll
            for (int kk = 0; kk < 4; kk++) {
                int k = (kg << 2) + kk;
                const float* wrow = wp + (size_t)k * (2 * IN_DIM);
                float2 w0 = *(const float2*)wrow;
                float2 w1 = *(const float2*)(wrow + 128);
                float2 w2 = *(const float2*)(wrow + 256);
#pragma unroll
                for (int n = 0; n < 4; n++) {
                    float t = mx[n][0].x * w0.x;
                    t = fmaf(mx[n][0].y, w0.y, t);
                    t = fmaf(mx[n][1].x, w1.x, t);
                    t = fmaf(mx[n][1].y, w1.y, t);
                    t = fmaf(mx[n][2].x, w2.x, t);
                    t = fmaf(mx[n][2].y, w2.y, t);
                    r[(n << 2) + kk] = t;
                }
            }
#pragma unroll
            for (int st = 0; st < 4; st++) {
                int step = 1 << st;
                bool hi = (lane & step) != 0;
#pragma unroll
                for (int m = 0; m < (8 >> st); m++) {
                    float a = r[2 * m], b = r[2 * m + 1];
                    float send = hi ? a : b;
                    float keep = hi ? b : a;
                    r[m] = keep + __shfl_xor(send, step, 64);
                }
            }
            float v = r[0];
            v += __shfl_xor(v, 16, 64);
            v += __shfl_xor(v, 32, 64);
            if ((lane >> 4) == kg) outv = v;
        }
        // epilogue: lane owns (node nq, channel kq); contiguous h-write
        int iw = ibase + nq;
        float t0 = __shfl(sd[0], kq, 64), t1 = __shfl(sd[1], kq, 64);
        float t2 = __shfl(sd[2], kq, 64), t3 = __shfl(sd[3], kq, 64);
        float sv = (nq == 0) ? t0 : (nq == 1) ? t1 : (nq == 2) ? t2 : t3;
        int dgs = (nq == 0) ? dgv[0] : (nq == 1) ? dgv[1] : (nq == 2) ? dgv[2] : dgv[3];
        if (iw < N) {
            float mean = sv / (float)max(dgs, 1);
            float hv = mean + outv + y[(size_t)iw * 32 + 16 + kq] + lb[kq];
            h[(size_t)iw * HID + kq] = hv;
            sAcc += hv;
            s2Acc = fmaf(hv, hv, s2Acc);
        }
    }
    __syncthreads();
    atomicAdd(&shS[kq], sAcc);
    atomicAdd(&shS[16 + kq], s2Acc);
    __syncthreads();
    if (threadIdx.x < 32) atomicAdd(&stats[threadIdx.x], shS[threadIdx.x]);
}

// ---------------- BN + ReLU + global mean pool + (last block) FC
__global__ __launch_bounds__(256) void k_pool(const float* __restrict__ h,
                                              const int* __restrict__ batch,
                                              const float* __restrict__ stats,
                                              const float* __restrict__ gamma,
                                              const float* __restrict__ beta, int N,
                                              float* __restrict__ pooled,
                                              int* __restrict__ gcnt,
                                              int* __restrict__ ticket,
                                              const float* __restrict__ fcw,
                                              const float* __restrict__ fcb, int G,
                                              float* __restrict__ out) {
    __shared__ float smP[MAXG * HID];
    __shared__ int smC[MAXG];
    __shared__ int isLast;
    for (int idx = threadIdx.x; idx < MAXG * HID; idx += blockDim.x) smP[idx] = 0.f;
    if (threadIdx.x < MAXG) smC[threadIdx.x] = 0;
    __syncthreads();
    int c = threadIdx.x & 15;
    float invN = 1.f / (float)N;
    float mu = stats[c] * invN;
    float var = stats[16 + c] * invN - mu * mu;
    float sc = gamma[c] * rsqrtf(var + BN_EPS);
    float sh = beta[c] - mu * sc;
    int base = blockIdx.x * 1024;
    int endn = min(base + 1024, N);
    for (int idx = base * HID + threadIdx.x; idx < endn * HID; idx += blockDim.x) {
        int n = idx >> 4;
        float v = fmaxf(fmaf(h[idx], sc, sh), 0.f);
        int g = batch[n] & (MAXG - 1);
        atomicAdd(&smP[g * HID + c], v);
        if (c == 0) atomicAdd(&smC[g], 1);
    }
    __syncthreads();
    for (int idx = threadIdx.x; idx < MAXG * HID; idx += blockDim.x)
        if (smP[idx] != 0.f) atomicAdd(&pooled[idx], smP[idx]);
    if (threadIdx.x < MAXG && smC[threadIdx.x]) atomicAdd(&gcnt[threadIdx.x], smC[threadIdx.x]);
    __threadfence();
    __syncthreads();
    if (threadIdx.x == 0) {
        int t = atomicAdd(ticket, 1);
        isLast = (t == (int)gridDim.x - 1);
    }
    __syncthreads();
    if (isLast && threadIdx.x < G) {
        int g = threadIdx.x;
        __threadfence();
        int cnt = atomicAdd(&gcnt[g], 0);  // coherent read (cross-XCD safe)
        float inv = 1.f / (float)max(cnt, 1);
        float o0 = fcb[0], o1 = fcb[1];
#pragma unroll
        for (int chh = 0; chh < HID; chh++) {
            float pv = atomicAdd(&pooled[g * HID + chh], 0.f) * inv;
            o0 = fmaf(pv, fcw[chh], o0);
            o1 = fmaf(pv, fcw[HID + chh], o1);
        }
        out[g * NCLS + 0] = o0;
        out[g * NCLS + 1] = o1;
    }
}

extern "C" void kernel_launch(void* const* d_in, const int* in_sizes, int n_in,
                              void* d_out, int out_size, void* d_ws, size_t ws_size,
                              hipStream_t stream) {
    const float* x = (const float*)d_in[0];
    const int* ei = (const int*)d_in[1];
    const int* batch = (const int*)d_in[2];
    const float* wl = (const float*)d_in[4];
    const float* lb = (const float*)d_in[5];
    const float* wr = (const float*)d_in[6];
    const float* gamma = (const float*)d_in[7];
    const float* beta = (const float*)d_in[8];
    const float* fcw = (const float*)d_in[9];
    const float* fcb = (const float*)d_in[10];

    const int N = in_sizes[0] / IN_DIM;
    const int E = in_sizes[1] / 2;
    const int G = out_size / NCLS;
    const int* ej = ei + E;

    size_t off = 0;
    auto take = [&](size_t b) { size_t r = off; off += (b + 255) & ~(size_t)255; return r; };
    size_t deg_off  = take((size_t)N * 4);
    size_t cur_off  = take(4);
    size_t stat_off = take(32 * 4);
    size_t pool_off = take((size_t)MAXG * HID * 4);
    size_t gcnt_off = take((size_t)MAXG * 4);
    size_t tick_off = take(4);
    size_t zero_bytes = off;
    size_t dof_off  = take((size_t)N * 8);
    size_t wcur_off = take((size_t)N * 4);
    size_t col_off  = take((size_t)E * 4);
    size_t y_off    = take((size_t)N * 32 * 4);
    size_t h_off    = take((size_t)N * HID * 4);
    size_t xb_off   = take((size_t)N * 192 * 4);
    size_t wbm_off  = take(16 * 192 * 4);
    size_t wbr_off  = take(16 * 192 * 4);
    (void)ws_size;

    char* ws = (char*)d_ws;
    int* deg = (int*)(ws + deg_off);
    int* cursor = (int*)(ws + cur_off);
    float* stats = (float*)(ws + stat_off);
    float* pooled = (float*)(ws + pool_off);
    int* gcnt = (int*)(ws + gcnt_off);
    int* ticket = (int*)(ws + tick_off);
    int2* degoffs = (int2*)(ws + dof_off);
    int* wcur = (int*)(ws + wcur_off);
    int* colidx = (int*)(ws + col_off);
    float* y = (float*)(ws + y_off);
    float* h = (float*)(ws + h_off);
    unsigned* xb = (unsigned*)(ws + xb_off);
    unsigned* wbm = (unsigned*)(ws + wbm_off);
    unsigned* wbr = (unsigned*)(ws + wbr_off);

    hipMemsetAsync(d_ws, 0, zero_bytes, stream);

    int eblocks = (E + 255) / 256;
    int ngroups = (N + 3) >> 2;
    int gblocks = (ngroups + 3) / 4;
    int ntiles = (N + 15) >> 4;
    int pblocks = (ntiles + 3) / 4;
    k_hist<<<eblocks, 256, 0, stream>>>(ei, E, deg, wl, wr, wbm, wbr);
    k_alloc<<<(N + 255) / 256, 256, 0, stream>>>(deg, N, degoffs, wcur, cursor);
    k_scatter<<<eblocks, 256, 0, stream>>>(ei, ej, E, wcur, colidx);
    k_proj<<<pblocks, 256, 0, stream>>>(x, wbm, wbr, N, y, xb);
    k_node<<<gblocks, 256, 0, stream>>>(xb, y, wl, lb, degoffs, colidx, N, h, stats);
    k_pool<<<(N + 1023) / 1024, 256, 0, stream>>>(h, batch, stats, gamma, beta, N, pooled,
                                                  gcnt, ticket, fcw, fcb, G, (float*)d_out);
}